// Round 11
// baseline (9029.887 us; speedup 1.0000x reference)
//
#include <hip/hip_runtime.h>
#include <hip/hip_cooperative_groups.h>
#include <cstdint>
#include <cstddef>

namespace cg = cooperative_groups;

// (B, H, D, STEP) = (2048, 512, 256, 64)
constexpr int NB  = 2048;
constexpr int NH  = 512;
constexpr int ND  = 256;
constexpr int NT  = 64;
constexpr int N4H = 2048;
constexpr int NBLK = 512;   // coop grid: 2 blocks/CU (48KB LDS each)

typedef __attribute__((ext_vector_type(8))) __bf16 bf16x8;
typedef __attribute__((ext_vector_type(4))) float  f32x4;

__device__ inline unsigned short f2bf_rne(float f) {
    unsigned u = __builtin_bit_cast(unsigned, f);
    unsigned r = (u + 0x7FFFu + ((u >> 16) & 1u)) >> 16;
    return (unsigned short)r;
}
__device__ inline float bf2f(unsigned short h) {
    unsigned u = ((unsigned)h) << 16;
    return __builtin_bit_cast(float, u);
}

// ---------------- prep: combine weights, split bf16 hi/lo, reorder Wsum rows,
// init cc from c, zero h.
__global__ __launch_bounds__(256) void prep_kernel(
    const float* __restrict__ c,   const float* __restrict__ Wih,
    const float* __restrict__ Whh, const float* __restrict__ bih,
    const float* __restrict__ bhh, const float* __restrict__ Whr,
    float* __restrict__ cc, float* __restrict__ bsum,
    unsigned short* __restrict__ WrH,  unsigned short* __restrict__ WrL,
    unsigned short* __restrict__ WhrH, unsigned short* __restrict__ WhrL,
    unsigned short* __restrict__ hH,   unsigned short* __restrict__ hL)
{
    int i = blockIdx.x * 256 + threadIdx.x;        // 0 .. NB*NH-1 (1M)
    cc[i] = c[i];                                  // c is (B,H,1) contiguous
    if (i < N4H) bsum[i] = bih[i] + bhh[i];
    if (i < N4H * ND) {                            // Wr reorder+split; h zero
        int np = i >> 8, k = i & 255;
        int jg = np >> 7, r = np & 127, g = r >> 5, cu = r & 31;
        int src = (g * NH + jg * 32 + cu) * ND + k;
        float w = Wih[src] + Whh[src];
        unsigned short hi = f2bf_rne(w);
        WrH[i] = hi; WrL[i] = f2bf_rne(w - bf2f(hi));
        hH[i] = 0; hL[i] = 0;                      // NB*ND == N4H*ND
    }
    if (i < ND * NH) {                             // Whr split ([256][512])
        float w = Whr[i];
        unsigned short hi = f2bf_rne(w);
        WhrH[i] = hi; WhrL[i] = f2bf_rne(w - bf2f(hi));
    }
}

// ---- stage one ROWSx64-elem bf16 tile into LDS via global_load_lds width 16.
// LDS dest: linear, wave-uniform base + lane*16. Global src: per-lane, pre-swizzled
// (kb ^ ((row&7)<<4)) so swizzled ds_reads see logical data (rule #21).
template <int ROWS>
__device__ __forceinline__ void stage_tile(const unsigned short* __restrict__ g,
                                           int row0, int ldgElems, int k0Elems,
                                           char* smem, int ldsOff, int wave, int lane)
{
    constexpr int QN = ROWS / 32;                       // 1KB per q per wave
#pragma unroll
    for (int q = 0; q < QN; ++q) {
        int L   = wave * (ROWS * 32) + q * 1024 + lane * 16;  // tile-local byte off
        int row = L >> 7;
        int kb  = L & 127;
        int kbs = kb ^ ((row & 7) << 4);
        const char* src = (const char*)g +
            (size_t)(row0 + row) * (ldgElems * 2) + k0Elems * 2 + kbs;
        char* dst = smem + ldsOff + wave * (ROWS * 32) + q * 1024;  // wave-uniform
        __builtin_amdgcn_global_load_lds(
            (const __attribute__((address_space(1))) unsigned int*)src,
            (__attribute__((address_space(3))) unsigned int*)dst,
            16, 0, 0);
    }
}

__device__ __forceinline__ bf16x8 frag_ld(const char* smem, int off, int row, int kb) {
    int kbs = kb ^ ((row & 7) << 4);
    return *(const bf16x8*)(smem + off + row * 128 + kbs);
}

// ---------------- gates phase: tile 64(b) x 128(n'), K=256, 3-term split.
// (bx, ny) = block's tile indices in (32, 16) space.
__device__ __forceinline__ void gates_phase(
    char* smem, int bx, int ny, int tid,
    const unsigned short* __restrict__ hH, const unsigned short* __restrict__ hL,
    const unsigned short* __restrict__ WrH, const unsigned short* __restrict__ WrL,
    const float* __restrict__ bsum, float* __restrict__ cc,
    unsigned short* __restrict__ aH, unsigned short* __restrict__ aL)
{
    constexpr int AsH = 0, AsL = 8192, BsH = 16384, BsL = 32768;
    const int lane = tid & 63;
    const int wave = tid >> 6;
    const int wr = wave >> 1, wc = wave & 1;   // 2x2 waves of 32(b) x 64(n)
    const int b0 = bx * 64;
    const int n0 = ny * 128;

    f32x4 acc[2][4];
#pragma unroll
    for (int mi = 0; mi < 2; ++mi)
#pragma unroll
        for (int ni = 0; ni < 4; ++ni)
            acc[mi][ni] = f32x4{0.f, 0.f, 0.f, 0.f};

    const int lrow = lane & 15;
    const int lk   = (lane >> 4) * 16;    // k-group byte offset

#pragma unroll 1
    for (int ch = 0; ch < 4; ++ch) {
        __syncthreads();
        stage_tile<64> (hH,  b0, ND, ch * 64, smem, AsH, wave, lane);
        stage_tile<64> (hL,  b0, ND, ch * 64, smem, AsL, wave, lane);
        stage_tile<128>(WrH, n0, ND, ch * 64, smem, BsH, wave, lane);
        stage_tile<128>(WrL, n0, ND, ch * 64, smem, BsL, wave, lane);
        __syncthreads();
#pragma unroll
        for (int kk = 0; kk < 2; ++kk) {
            const int kb = kk * 64 + lk;
            bf16x8 aHf[2], aLf[2], bHf[4], bLf[4];
#pragma unroll
            for (int mi = 0; mi < 2; ++mi) {
                int row = wr * 32 + mi * 16 + lrow;
                aHf[mi] = frag_ld(smem, AsH, row, kb);
                aLf[mi] = frag_ld(smem, AsL, row, kb);
            }
#pragma unroll
            for (int ni = 0; ni < 4; ++ni) {
                int row = wc * 64 + ni * 16 + lrow;
                bHf[ni] = frag_ld(smem, BsH, row, kb);
                bLf[ni] = frag_ld(smem, BsL, row, kb);
            }
#pragma unroll
            for (int mi = 0; mi < 2; ++mi)
#pragma unroll
                for (int ni = 0; ni < 4; ++ni) {
                    acc[mi][ni] = __builtin_amdgcn_mfma_f32_16x16x32_bf16(aHf[mi], bHf[ni], acc[mi][ni], 0, 0, 0);
                    acc[mi][ni] = __builtin_amdgcn_mfma_f32_16x16x32_bf16(aHf[mi], bLf[ni], acc[mi][ni], 0, 0, 0);
                    acc[mi][ni] = __builtin_amdgcn_mfma_f32_16x16x32_bf16(aLf[mi], bHf[ni], acc[mi][ni], 0, 0, 0);
                }
        }
    }
    __syncthreads();                      // frag reads done; reuse smem as z
    float (*z)[128] = (float(*)[128])smem;
#pragma unroll
    for (int mi = 0; mi < 2; ++mi)
#pragma unroll
        for (int ni = 0; ni < 4; ++ni)
#pragma unroll
            for (int r = 0; r < 4; ++r) {
                int m = wr * 32 + mi * 16 + (lane >> 4) * 4 + r;
                int n = wc * 64 + ni * 16 + (lane & 15);
                z[m][n] = acc[mi][ni][r];
            }
    __syncthreads();
    // epilogue: n-tile covers 32 h-cols x 4 gates (gate-stride 32 via W reorder)
    const int cu = tid & 31;
    const int rg = tid >> 5;              // 0..7
    const int j  = ny * 32 + cu;
    const float bi = bsum[0 * NH + j], bfv = bsum[1 * NH + j];
    const float bg = bsum[2 * NH + j], bo  = bsum[3 * NH + j];
#pragma unroll
    for (int it = 0; it < 8; ++it) {
        int m = rg * 8 + it;
        size_t idx = (size_t)(b0 + m) * NH + j;
        float zi = z[m][cu]      + bi;
        float zf = z[m][32 + cu] + bfv;
        float zg = z[m][64 + cu] + bg;
        float zo = z[m][96 + cu] + bo;
        float iv = 1.f / (1.f + expf(-zi));
        float fv = 1.f / (1.f + expf(-zf));
        float gv = tanhf(zg);
        float ov = 1.f / (1.f + expf(-zo));
        float cv = fv * cc[idx] + iv * gv;
        cc[idx] = cv;
        float av = ov * tanhf(cv);
        unsigned short ah = f2bf_rne(av);
        aH[idx] = ah;
        aL[idx] = f2bf_rne(av - bf2f(ah));
    }
}

// ---------------- recur phase: tile 32(b) x 32(d), K=512, 3-term.
// (bxr, dyr) in (64, 8) space. 4 waves 2x2, each 16x16 output.
template <bool STAGED>
__device__ __forceinline__ void recur_phase(
    char* smem, int bxr, int dyr, int tid,
    const unsigned short* __restrict__ aH, const unsigned short* __restrict__ aL,
    const unsigned short* __restrict__ WhrHp, const unsigned short* __restrict__ WhrLp,
    unsigned short* __restrict__ hH, unsigned short* __restrict__ hL,
    float* __restrict__ hseq, float* __restrict__ out, int t)
{
    constexpr int AsH = 0, AsL = 4096, BsH = 8192, BsL = 12288;
    const int lane = tid & 63;
    const int wave = tid >> 6;
    const int wr = wave >> 1, wc = wave & 1;
    const int b0 = bxr * 32;
    const int d0 = dyr * 32;

    f32x4 acc = f32x4{0.f, 0.f, 0.f, 0.f};

    const int lrow = lane & 15;
    const int lk   = (lane >> 4) * 16;

#pragma unroll 1
    for (int ch = 0; ch < 8; ++ch) {
        __syncthreads();
        stage_tile<32>(aH,    b0, NH, ch * 64, smem, AsH, wave, lane);
        stage_tile<32>(aL,    b0, NH, ch * 64, smem, AsL, wave, lane);
        stage_tile<32>(WhrHp, d0, NH, ch * 64, smem, BsH, wave, lane);
        stage_tile<32>(WhrLp, d0, NH, ch * 64, smem, BsL, wave, lane);
        __syncthreads();
#pragma unroll
        for (int kk = 0; kk < 2; ++kk) {
            const int kb = kk * 64 + lk;
            int arow = wr * 16 + lrow;
            int brow = wc * 16 + lrow;
            bf16x8 aHf = frag_ld(smem, AsH, arow, kb);
            bf16x8 aLf = frag_ld(smem, AsL, arow, kb);
            bf16x8 bHf = frag_ld(smem, BsH, brow, kb);
            bf16x8 bLf = frag_ld(smem, BsL, brow, kb);
            acc = __builtin_amdgcn_mfma_f32_16x16x32_bf16(aHf, bHf, acc, 0, 0, 0);
            acc = __builtin_amdgcn_mfma_f32_16x16x32_bf16(aHf, bLf, acc, 0, 0, 0);
            acc = __builtin_amdgcn_mfma_f32_16x16x32_bf16(aLf, bHf, acc, 0, 0, 0);
        }
    }
#pragma unroll
    for (int r = 0; r < 4; ++r) {
        int b = b0 + wr * 16 + (lane >> 4) * 4 + r;
        int d = d0 + wc * 16 + (lane & 15);
        float v = acc[r];
        if (STAGED) hseq[((size_t)t * NB + b) * ND + d] = v;
        else        out[((size_t)b * ND + d) * NT + t]  = v;
        size_t hidx = (size_t)b * ND + d;
        unsigned short hh = f2bf_rne(v);
        hH[hidx] = hh;
        hL[hidx] = f2bf_rne(v - bf2f(hh));
    }
}

// ---------------- fused persistent kernel: 64 steps, official grid sync.
// 512 blocks (2/CU at 48KB LDS); gates map (blk>>4, blk&15), recur (blk>>3, blk&7).
template <bool STAGED>
__global__ __launch_bounds__(256) void lstm_coop(
    unsigned short* hH, unsigned short* hL,
    const unsigned short* WrH, const unsigned short* WrL,
    const unsigned short* WhrH, const unsigned short* WhrL,
    const float* bsum, float* cc,
    unsigned short* aH, unsigned short* aL,
    float* hseq, float* out)
{
    __shared__ char smem[49152];
    const int blk = blockIdx.x;
    const int tid = threadIdx.x;
    cg::grid_group grid = cg::this_grid();
#pragma unroll 1
    for (int t = 0; t < NT; ++t) {
        gates_phase(smem, blk >> 4, blk & 15, tid, hH, hL, WrH, WrL, bsum, cc, aH, aL);
        grid.sync();
        recur_phase<STAGED>(smem, blk >> 3, blk & 7, tid, aH, aL, WhrH, WhrL,
                            hH, hL, hseq, out, t);
        grid.sync();
    }
}

// ---------------- fallback per-step wrappers (validated R9 configuration)
__global__ __launch_bounds__(256) void gates_step(
    const unsigned short* hH, const unsigned short* hL,
    const unsigned short* WrH, const unsigned short* WrL,
    const float* bsum, float* cc, unsigned short* aH, unsigned short* aL)
{
    __shared__ char smem[49152];
    gates_phase(smem, blockIdx.x, blockIdx.y, threadIdx.x,
                hH, hL, WrH, WrL, bsum, cc, aH, aL);
}

template <bool STAGED>
__global__ __launch_bounds__(256) void recur_step(
    const unsigned short* aH, const unsigned short* aL,
    const unsigned short* WhrH, const unsigned short* WhrL,
    unsigned short* hH, unsigned short* hL,
    float* hseq, float* out, int t)
{
    __shared__ char smem[16384];
    recur_phase<STAGED>(smem, blockIdx.x, blockIdx.y, threadIdx.x,
                        aH, aL, WhrH, WhrL, hH, hL, hseq, out, t);
}

// ---------------- final transpose: hseq (t,b,d) -> out (b,d,t)
__global__ __launch_bounds__(256) void transpose_kernel(
    const float* __restrict__ hseq, float* __restrict__ out) {
    __shared__ float tile[64][65];
    const int tid = threadIdx.x;
    const int d0  = blockIdx.x * 64;
    const int b   = blockIdx.y;
    const int x   = tid & 63;
    const int y   = tid >> 6;  // 0..3
#pragma unroll
    for (int r = 0; r < 16; ++r) {
        int t = y + r * 4;
        tile[t][x] = hseq[((size_t)t * NB + b) * ND + d0 + x];
    }
    __syncthreads();
#pragma unroll
    for (int r = 0; r < 16; ++r) {
        int d = y + r * 4;
        out[((size_t)b * ND + d0 + d) * NT + x] = tile[x][d];
    }
}

extern "C" void kernel_launch(void* const* d_in, const int* in_sizes, int n_in,
                              void* d_out, int out_size, void* d_ws, size_t ws_size,
                              hipStream_t stream) {
    const float* c   = (const float*)d_in[0];
    const float* Wih = (const float*)d_in[1];
    const float* Whh = (const float*)d_in[2];
    const float* bih = (const float*)d_in[3];
    const float* bhh = (const float*)d_in[4];
    const float* Whr = (const float*)d_in[5];
    float* out = (float*)d_out;

    char* ws = (char*)d_ws;
    size_t off = 0;
    auto alloc = [&](size_t bytes) -> char* {
        char* p = ws + off;
        off = (off + bytes + 255) & ~(size_t)255;
        return p;
    };
    float*          cc    = (float*)alloc((size_t)NB * NH * 4);
    float*          bsum  = (float*)alloc((size_t)N4H * 4);
    unsigned short* WrHp  = (unsigned short*)alloc((size_t)N4H * ND * 2);
    unsigned short* WrLp  = (unsigned short*)alloc((size_t)N4H * ND * 2);
    unsigned short* WhrHp = (unsigned short*)alloc((size_t)ND * NH * 2);
    unsigned short* WhrLp = (unsigned short*)alloc((size_t)ND * NH * 2);
    unsigned short* hH    = (unsigned short*)alloc((size_t)NB * ND * 2);
    unsigned short* hL    = (unsigned short*)alloc((size_t)NB * ND * 2);
    unsigned short* aH    = (unsigned short*)alloc((size_t)NB * NH * 2);
    unsigned short* aL    = (unsigned short*)alloc((size_t)NB * NH * 2);
    size_t hseq_bytes = (size_t)NT * NB * ND * 4;
    float* hseq = (float*)(ws + off);
    const bool staged = (off + hseq_bytes) <= ws_size;

    prep_kernel<<<(NB * NH) / 256, 256, 0, stream>>>(
        c, Wih, Whh, bih, bhh, Whr, cc, bsum, WrHp, WrLp, WhrHp, WhrLp, hH, hL);

    void* args[] = { &hH, &hL, &WrHp, &WrLp, &WhrHp, &WhrLp, &bsum, &cc,
                     &aH, &aL, &hseq, &out };
    hipError_t cerr = hipLaunchCooperativeKernel(
        staged ? (void*)lstm_coop<true> : (void*)lstm_coop<false>,
        dim3(NBLK), dim3(256), args, 0, stream);
    if (cerr != hipSuccess) {
        (void)hipGetLastError();   // clear sticky error; use per-step fallback
        dim3 g1(NB / 64, N4H / 128);   // (32,16) = 512 blocks
        dim3 g2(NB / 32, ND / 32);     // (64,8)  = 512 blocks
        for (int t = 0; t < NT; ++t) {
            gates_step<<<g1, 256, 0, stream>>>(hH, hL, WrHp, WrLp, bsum, cc, aH, aL);
            if (staged)
                recur_step<true><<<g2, 256, 0, stream>>>(aH, aL, WhrHp, WhrLp,
                                                         hH, hL, hseq, out, t);
            else
                recur_step<false><<<g2, 256, 0, stream>>>(aH, aL, WhrHp, WhrLp,
                                                          hH, hL, hseq, out, t);
        }
    }
    if (staged) {
        dim3 gt(ND / 64, NB);
        transpose_kernel<<<gt, 256, 0, stream>>>(hseq, out);
    }
}

// Round 12
// 1583.161 us; speedup vs baseline: 5.7037x; 5.7037x over previous
//
#include <hip/hip_runtime.h>
#include <cstdint>
#include <cstddef>

// (B, H, D, STEP) = (2048, 512, 256, 64)
constexpr int NB  = 2048;
constexpr int NH  = 512;
constexpr int ND  = 256;
constexpr int NT  = 64;
constexpr int N4H = 2048;
constexpr size_t SLOT = (size_t)NB * NH;   // one a-timestep (1M elems)

typedef __attribute__((ext_vector_type(8))) __bf16 bf16x8;
typedef __attribute__((ext_vector_type(4))) float  f32x4;

__device__ inline unsigned short f2bf_rne(float f) {
    unsigned u = __builtin_bit_cast(unsigned, f);
    unsigned r = (u + 0x7FFFu + ((u >> 16) & 1u)) >> 16;
    return (unsigned short)r;
}
__device__ inline float bf2f(unsigned short h) {
    unsigned u = ((unsigned)h) << 16;
    return __builtin_bit_cast(float, u);
}

// ---------------- prep1: cc=c, bsum, Wsum (fp32, gate-reordered rows), Whr split,
// zero slot 0 of a_seq (so step 0's GEMM yields z = bias exactly).
__global__ __launch_bounds__(256) void prep1_kernel(
    const float* __restrict__ c,   const float* __restrict__ Wih,
    const float* __restrict__ Whh, const float* __restrict__ bih,
    const float* __restrict__ bhh, const float* __restrict__ Whr,
    float* __restrict__ cc, float* __restrict__ bsum,
    float* __restrict__ Wsum_reord,
    unsigned short* __restrict__ WhrH, unsigned short* __restrict__ WhrL,
    unsigned short* __restrict__ aHseq, unsigned short* __restrict__ aLseq)
{
    int i = blockIdx.x * 256 + threadIdx.x;        // 0 .. NB*NH-1 (1M)
    cc[i] = c[i];                                  // c is (B,H,1) contiguous
    aHseq[i] = 0; aLseq[i] = 0;                    // slot 0 = zeros
    if (i < N4H) bsum[i] = bih[i] + bhh[i];
    if (i < N4H * ND) {                            // reorder: n' = jg*128+g*32+cu
        int np = i >> 8, k = i & 255;
        int jg = np >> 7, r = np & 127, g = r >> 5, cu = r & 31;
        int src = (g * NH + jg * 32 + cu) * ND + k;
        Wsum_reord[i] = Wih[src] + Whh[src];
    }
    if (i < ND * NH) {                             // Whr split ([256][512])
        float w = Whr[i];
        unsigned short hi = f2bf_rne(w);
        WhrH[i] = hi; WhrL[i] = f2bf_rne(w - bf2f(hi));
    }
}

// ---------------- prep2: Wbig = Wsum_reord @ Whr  ([2048 n'][512 h], fp32), split
// to bf16 hi/lo. Tile 64x64, K=256 in 4 chunks. One-time cost.
__global__ __launch_bounds__(256) void prep2_kernel(
    const float* __restrict__ Wsum_reord, const float* __restrict__ Whr,
    unsigned short* __restrict__ WbigH, unsigned short* __restrict__ WbigL)
{
    __shared__ float a_s[64][65];   // [k][n]
    __shared__ float b_s[64][68];   // [k][h]
    const int tid = threadIdx.x;
    const int n0 = blockIdx.x * 64;
    const int h0 = blockIdx.y * 64;
    const int r  = tid >> 2;        // 0..63
    const int q  = tid & 3;         // 0..3
    const int tn = (tid & 15) * 4;
    const int th = (tid >> 4) * 4;

    float acc[4][4] = {};
#pragma unroll 1
    for (int ch = 0; ch < 4; ++ch) {
        __syncthreads();
#pragma unroll
        for (int e = 0; e < 4; ++e) {   // A rows n0+r, k cols ch*64+q*16+e*4
            float4 v = *reinterpret_cast<const float4*>(
                &Wsum_reord[(size_t)(n0 + r) * ND + ch * 64 + q * 16 + e * 4]);
            int k = q * 16 + e * 4;
            a_s[k + 0][r] = v.x; a_s[k + 1][r] = v.y;
            a_s[k + 2][r] = v.z; a_s[k + 3][r] = v.w;
        }
#pragma unroll
        for (int e = 0; e < 4; ++e) {   // B row d=ch*64+r, cols h0+q*16+e*4
            float4 v = *reinterpret_cast<const float4*>(
                &Whr[(size_t)(ch * 64 + r) * NH + h0 + q * 16 + e * 4]);
            *reinterpret_cast<float4*>(&b_s[r][q * 16 + e * 4]) = v;
        }
        __syncthreads();
#pragma unroll 8
        for (int k = 0; k < 64; ++k) {
            float av[4], bv[4];
#pragma unroll
            for (int e = 0; e < 4; ++e) { av[e] = a_s[k][tn + e]; bv[e] = b_s[k][th + e]; }
#pragma unroll
            for (int ii = 0; ii < 4; ++ii)
#pragma unroll
                for (int jj = 0; jj < 4; ++jj)
                    acc[ii][jj] += av[ii] * bv[jj];
        }
    }
#pragma unroll
    for (int ii = 0; ii < 4; ++ii)
#pragma unroll
        for (int jj = 0; jj < 4; ++jj) {
            float w = acc[ii][jj];
            unsigned short hi = f2bf_rne(w);
            size_t idx = (size_t)(n0 + tn + ii) * NH + h0 + th + jj;
            WbigH[idx] = hi;
            WbigL[idx] = f2bf_rne(w - bf2f(hi));
        }
}

// ---- stage one ROWSx64-elem bf16 tile into LDS via global_load_lds width 16.
// LDS dest: linear, wave-uniform base + lane*16. Global src: per-lane, pre-swizzled
// (kb ^ ((row&7)<<4)) so swizzled ds_reads see logical data (rule #21).
template <int ROWS>
__device__ __forceinline__ void stage_tile(const unsigned short* __restrict__ g,
                                           int row0, int ldgElems, int k0Elems,
                                           char* smem, int ldsOff, int wave, int lane)
{
    constexpr int QN = ROWS / 32;                       // 1KB per q per wave
#pragma unroll
    for (int q = 0; q < QN; ++q) {
        int L   = wave * (ROWS * 32) + q * 1024 + lane * 16;  // tile-local byte off
        int row = L >> 7;
        int kb  = L & 127;
        int kbs = kb ^ ((row & 7) << 4);
        const char* src = (const char*)g +
            (size_t)(row0 + row) * (ldgElems * 2) + k0Elems * 2 + kbs;
        char* dst = smem + ldsOff + wave * (ROWS * 32) + q * 1024;  // wave-uniform
        __builtin_amdgcn_global_load_lds(
            (const __attribute__((address_space(1))) unsigned int*)src,
            (__attribute__((address_space(3))) unsigned int*)dst,
            16, 0, 0);
    }
}

__device__ __forceinline__ bf16x8 frag_ld(const char* smem, int off, int row, int kb) {
    int kbs = kb ^ ((row & 7) << 4);
    return *(const bf16x8*)(smem + off + row * 128 + kbs);
}

// ---------------- step kernel: z = a_{t-1} @ Wbig^T (+bias) -> gates -> cc -> a_t.
// Tile 64(b) x 128(n'), K=512 in 8 chunks, 3-term split. grid (32,16)=512 blocks,
// 48KB LDS -> 2 blocks/CU. Reads a-slot t, writes a-slot t+1.
__global__ __launch_bounds__(256) void step_kernel(
    const unsigned short* __restrict__ aHseq, const unsigned short* __restrict__ aLseq,
    const unsigned short* __restrict__ WbigH, const unsigned short* __restrict__ WbigL,
    const float* __restrict__ bsum, float* __restrict__ cc, int t)
{
    __shared__ char smem[49152];
    constexpr int AsH = 0, AsL = 8192, BsH = 16384, BsL = 32768;
    const int tid  = threadIdx.x;
    const int lane = tid & 63;
    const int wave = tid >> 6;
    const int wr = wave >> 1, wc = wave & 1;   // 2x2 waves of 32(b) x 64(n)
    const int b0 = blockIdx.x * 64;
    const int ny = blockIdx.y;
    const int n0 = ny * 128;

    const unsigned short* aH = aHseq + (size_t)t * SLOT;
    const unsigned short* aL = aLseq + (size_t)t * SLOT;

    f32x4 acc[2][4];
#pragma unroll
    for (int mi = 0; mi < 2; ++mi)
#pragma unroll
        for (int ni = 0; ni < 4; ++ni)
            acc[mi][ni] = f32x4{0.f, 0.f, 0.f, 0.f};

    const int lrow = lane & 15;
    const int lk   = (lane >> 4) * 16;

#pragma unroll 1
    for (int ch = 0; ch < 8; ++ch) {
        __syncthreads();
        stage_tile<64> (aH,    b0, NH, ch * 64, smem, AsH, wave, lane);
        stage_tile<64> (aL,    b0, NH, ch * 64, smem, AsL, wave, lane);
        stage_tile<128>(WbigH, n0, NH, ch * 64, smem, BsH, wave, lane);
        stage_tile<128>(WbigL, n0, NH, ch * 64, smem, BsL, wave, lane);
        __syncthreads();
#pragma unroll
        for (int kk = 0; kk < 2; ++kk) {
            const int kb = kk * 64 + lk;
            bf16x8 aHf[2], aLf[2], bHf[4], bLf[4];
#pragma unroll
            for (int mi = 0; mi < 2; ++mi) {
                int row = wr * 32 + mi * 16 + lrow;
                aHf[mi] = frag_ld(smem, AsH, row, kb);
                aLf[mi] = frag_ld(smem, AsL, row, kb);
            }
#pragma unroll
            for (int ni = 0; ni < 4; ++ni) {
                int row = wc * 64 + ni * 16 + lrow;
                bHf[ni] = frag_ld(smem, BsH, row, kb);
                bLf[ni] = frag_ld(smem, BsL, row, kb);
            }
#pragma unroll
            for (int mi = 0; mi < 2; ++mi)
#pragma unroll
                for (int ni = 0; ni < 4; ++ni) {
                    acc[mi][ni] = __builtin_amdgcn_mfma_f32_16x16x32_bf16(aHf[mi], bHf[ni], acc[mi][ni], 0, 0, 0);
                    acc[mi][ni] = __builtin_amdgcn_mfma_f32_16x16x32_bf16(aHf[mi], bLf[ni], acc[mi][ni], 0, 0, 0);
                    acc[mi][ni] = __builtin_amdgcn_mfma_f32_16x16x32_bf16(aLf[mi], bHf[ni], acc[mi][ni], 0, 0, 0);
                }
        }
    }
    __syncthreads();                      // frag reads done; reuse smem as z
    float (*z)[128] = (float(*)[128])smem;
#pragma unroll
    for (int mi = 0; mi < 2; ++mi)
#pragma unroll
        for (int ni = 0; ni < 4; ++ni)
#pragma unroll
            for (int r = 0; r < 4; ++r) {
                int m = wr * 32 + mi * 16 + (lane >> 4) * 4 + r;
                int n = wc * 64 + ni * 16 + (lane & 15);
                z[m][n] = acc[mi][ni][r];
            }
    __syncthreads();
    // epilogue: n-tile = 32 h-cols x 4 gates (gate-stride 32 via row reorder)
    const int cu = tid & 31;
    const int rg = tid >> 5;              // 0..7
    const int j  = ny * 32 + cu;
    const float bi = bsum[0 * NH + j], bfv = bsum[1 * NH + j];
    const float bg = bsum[2 * NH + j], bo  = bsum[3 * NH + j];
    unsigned short* aHo = (unsigned short*)aHseq + (size_t)(t + 1) * SLOT;
    unsigned short* aLo = (unsigned short*)aLseq + (size_t)(t + 1) * SLOT;
#pragma unroll
    for (int it = 0; it < 8; ++it) {
        int m = rg * 8 + it;
        size_t idx = (size_t)(b0 + m) * NH + j;
        float zi = z[m][cu]      + bi;
        float zf = z[m][32 + cu] + bfv;
        float zg = z[m][64 + cu] + bg;
        float zo = z[m][96 + cu] + bo;
        float iv = 1.f / (1.f + expf(-zi));
        float fv = 1.f / (1.f + expf(-zf));
        float gv = tanhf(zg);
        float ov = 1.f / (1.f + expf(-zo));
        float cv = fv * cc[idx] + iv * gv;
        cc[idx] = cv;
        float av = ov * tanhf(cv);
        unsigned short ah = f2bf_rne(av);
        aHo[idx] = ah;
        aLo[idx] = f2bf_rne(av - bf2f(ah));
    }
}

// ---------------- batched y GEMM: y_t = a_t @ Whr^T for all t (off critical path).
// Tile 64(b) x 128(d), K=512, 3-term. grid (32, 2, 64). DIRECT: write out strided.
template <bool DIRECT>
__global__ __launch_bounds__(256) void y_kernel(
    const unsigned short* __restrict__ aHseq, const unsigned short* __restrict__ aLseq,
    const unsigned short* __restrict__ WhrH, const unsigned short* __restrict__ WhrL,
    float* __restrict__ hseq, float* __restrict__ out)
{
    __shared__ char smem[49152];
    constexpr int AsH = 0, AsL = 8192, BsH = 16384, BsL = 32768;
    const int tid  = threadIdx.x;
    const int lane = tid & 63;
    const int wave = tid >> 6;
    const int wr = wave >> 1, wc = wave & 1;
    const int b0 = blockIdx.x * 64;
    const int d0 = blockIdx.y * 128;
    const int t  = blockIdx.z;

    const unsigned short* aH = aHseq + (size_t)(t + 1) * SLOT;
    const unsigned short* aL = aLseq + (size_t)(t + 1) * SLOT;

    f32x4 acc[2][4];
#pragma unroll
    for (int mi = 0; mi < 2; ++mi)
#pragma unroll
        for (int ni = 0; ni < 4; ++ni)
            acc[mi][ni] = f32x4{0.f, 0.f, 0.f, 0.f};

    const int lrow = lane & 15;
    const int lk   = (lane >> 4) * 16;

#pragma unroll 1
    for (int ch = 0; ch < 8; ++ch) {
        __syncthreads();
        stage_tile<64> (aH,   b0, NH, ch * 64, smem, AsH, wave, lane);
        stage_tile<64> (aL,   b0, NH, ch * 64, smem, AsL, wave, lane);
        stage_tile<128>(WhrH, d0, NH, ch * 64, smem, BsH, wave, lane);
        stage_tile<128>(WhrL, d0, NH, ch * 64, smem, BsL, wave, lane);
        __syncthreads();
#pragma unroll
        for (int kk = 0; kk < 2; ++kk) {
            const int kb = kk * 64 + lk;
            bf16x8 aHf[2], aLf[2], bHf[4], bLf[4];
#pragma unroll
            for (int mi = 0; mi < 2; ++mi) {
                int row = wr * 32 + mi * 16 + lrow;
                aHf[mi] = frag_ld(smem, AsH, row, kb);
                aLf[mi] = frag_ld(smem, AsL, row, kb);
            }
#pragma unroll
            for (int ni = 0; ni < 4; ++ni) {
                int row = wc * 64 + ni * 16 + lrow;
                bHf[ni] = frag_ld(smem, BsH, row, kb);
                bLf[ni] = frag_ld(smem, BsL, row, kb);
            }
#pragma unroll
            for (int mi = 0; mi < 2; ++mi)
#pragma unroll
                for (int ni = 0; ni < 4; ++ni) {
                    acc[mi][ni] = __builtin_amdgcn_mfma_f32_16x16x32_bf16(aHf[mi], bHf[ni], acc[mi][ni], 0, 0, 0);
                    acc[mi][ni] = __builtin_amdgcn_mfma_f32_16x16x32_bf16(aHf[mi], bLf[ni], acc[mi][ni], 0, 0, 0);
                    acc[mi][ni] = __builtin_amdgcn_mfma_f32_16x16x32_bf16(aLf[mi], bHf[ni], acc[mi][ni], 0, 0, 0);
                }
        }
    }
#pragma unroll
    for (int mi = 0; mi < 2; ++mi)
#pragma unroll
        for (int ni = 0; ni < 4; ++ni)
#pragma unroll
            for (int r = 0; r < 4; ++r) {
                int b = b0 + wr * 32 + mi * 16 + (lane >> 4) * 4 + r;
                int d = d0 + wc * 64 + ni * 16 + (lane & 15);
                float v = acc[mi][ni][r];
                if (DIRECT) out[((size_t)b * ND + d) * NT + t] = v;
                else        hseq[((size_t)t * NB + b) * ND + d] = v;
            }
}

// ---------------- final transpose: hseq (t,b,d) -> out (b,d,t)
__global__ __launch_bounds__(256) void transpose_kernel(
    const float* __restrict__ hseq, float* __restrict__ out) {
    __shared__ float tile[64][65];
    const int tid = threadIdx.x;
    const int d0  = blockIdx.x * 64;
    const int b   = blockIdx.y;
    const int x   = tid & 63;
    const int y   = tid >> 6;  // 0..3
#pragma unroll
    for (int r = 0; r < 16; ++r) {
        int t = y + r * 4;
        tile[t][x] = hseq[((size_t)t * NB + b) * ND + d0 + x];
    }
    __syncthreads();
#pragma unroll
    for (int r = 0; r < 16; ++r) {
        int d = y + r * 4;
        out[((size_t)b * ND + d0 + d) * NT + x] = tile[x][d];
    }
}

extern "C" void kernel_launch(void* const* d_in, const int* in_sizes, int n_in,
                              void* d_out, int out_size, void* d_ws, size_t ws_size,
                              hipStream_t stream) {
    const float* c   = (const float*)d_in[0];
    const float* Wih = (const float*)d_in[1];
    const float* Whh = (const float*)d_in[2];
    const float* bih = (const float*)d_in[3];
    const float* bhh = (const float*)d_in[4];
    const float* Whr = (const float*)d_in[5];
    float* out = (float*)d_out;

    char* ws = (char*)d_ws;
    size_t off = 0;
    auto alloc = [&](size_t bytes) -> char* {
        char* p = ws + off;
        off = (off + bytes + 255) & ~(size_t)255;
        return p;
    };
    float*          cc     = (float*)alloc((size_t)NB * NH * 4);
    float*          bsum   = (float*)alloc((size_t)N4H * 4);
    float*          Wsum_r = (float*)alloc((size_t)N4H * ND * 4);
    unsigned short* WbigH  = (unsigned short*)alloc((size_t)N4H * NH * 2);
    unsigned short* WbigL  = (unsigned short*)alloc((size_t)N4H * NH * 2);
    unsigned short* WhrH   = (unsigned short*)alloc((size_t)ND * NH * 2);
    unsigned short* WhrL   = (unsigned short*)alloc((size_t)ND * NH * 2);
    unsigned short* aHseq  = (unsigned short*)alloc((NT + 1) * SLOT * 2);
    unsigned short* aLseq  = (unsigned short*)alloc((NT + 1) * SLOT * 2);
    size_t hseq_bytes = (size_t)NT * NB * ND * 4;
    float* hseq = (float*)(ws + off);
    const bool staged = (off + hseq_bytes) <= ws_size;

    prep1_kernel<<<(NB * NH) / 256, 256, 0, stream>>>(
        c, Wih, Whh, bih, bhh, Whr, cc, bsum, Wsum_r, WhrH, WhrL, aHseq, aLseq);
    prep2_kernel<<<dim3(N4H / 64, NH / 64), 256, 0, stream>>>(
        Wsum_r, Whr, WbigH, WbigL);

    dim3 gs(NB / 64, N4H / 128);   // (32,16) = 512 blocks
    for (int t = 0; t < NT; ++t)
        step_kernel<<<gs, 256, 0, stream>>>(aHseq, aLseq, WbigH, WbigL, bsum, cc, t);

    dim3 gy(NB / 64, ND / 128, NT);   // (32,2,64)
    if (staged) {
        y_kernel<false><<<gy, 256, 0, stream>>>(aHseq, aLseq, WhrH, WhrL, hseq, out);
        dim3 gt(ND / 64, NB);
        transpose_kernel<<<gt, 256, 0, stream>>>(hseq, out);
    } else {
        y_kernel<true><<<gy, 256, 0, stream>>>(aHseq, aLseq, WhrH, WhrL, hseq, out);
    }
}